// Round 3
// baseline (686.144 us; speedup 1.0000x reference)
//
#include <hip/hip_runtime.h>

#define SEQ 550
#define MID 100
#define TPB 128

typedef _Float16 half2_t __attribute__((ext_vector_type(2)));
typedef _Float16 half8_t __attribute__((ext_vector_type(8)));
typedef float f32x4 __attribute__((ext_vector_type(4)));

union H2I { int i; half2_t h; };
union H8I { int4 i4; half8_t h8; };

__device__ __forceinline__ float fdot2(half2_t a, half2_t b, float c) {
    return __builtin_amdgcn_fdot2(a, b, c, false);
}
__device__ __forceinline__ float sigm(float x) { return 1.0f / (1.0f + __expf(-x)); }
__device__ __forceinline__ float tanh_f(float x) { return 1.0f - 2.0f / (__expf(2.0f * x) + 1.0f); }
__device__ __forceinline__ half2_t i2h(int v) { H2I u; u.i = v; return u.h; }
// quad_perm [1,0,3,2]: even lane receives odd neighbor's value
__device__ __forceinline__ float pull_odd(float x) {
    int y = __builtin_amdgcn_update_dpp(0, __float_as_int(x), 0xB1, 0xF, 0xF, true);
    return __int_as_float(y);
}

// One group of MFMA row-tiles: 3 chained k-slices each, then col-0 lanes store D.
template<int BASE, int CNT>
__device__ __forceinline__ void mfma_group(const half8_t (&afr)[19][3],
                                           half8_t b0, half8_t b1, half8_t b2,
                                           f32x4 zf, char* gw, int m) {
    f32x4 dd[CNT];
    #pragma unroll
    for (int j = 0; j < CNT; j++) {
        f32x4 d = __builtin_amdgcn_mfma_f32_16x16x32_f16(afr[BASE + j][0], b0, zf, 0, 0, 0);
        d = __builtin_amdgcn_mfma_f32_16x16x32_f16(afr[BASE + j][1], b1, d, 0, 0, 0);
        d = __builtin_amdgcn_mfma_f32_16x16x32_f16(afr[BASE + j][2], b2, d, 0, 0, 0);
        dd[j] = d;
    }
    if (m == 0) {
        #pragma unroll
        for (int j = 0; j < CNT; j++)
            *(f32x4*)(gw + 64 * (BASE + j)) = dd[j];
    }
}

__global__ __launch_bounds__(TPB, 1) void gru_fused(
    const int*   __restrict__ x,
    const float* __restrict__ hidden,
    const float* __restrict__ embed,
    const float* __restrict__ w_ih,
    const float* __restrict__ w_hh,
    const float* __restrict__ b_ih,
    const float* __restrict__ b_hh,
    const float* __restrict__ fc_w,
    const float* __restrict__ fc_b,
    float*       __restrict__ out)
{
    __shared__ __align__(16) int   seqbuf[SEQ * 8];   // e_t: 5 packed half2 + pad, stride 8 dwords
    __shared__ __align__(16) int   gates[340];        // rows 0..303 (f32), + slack for junk reads
    __shared__ __align__(16) int   hbuf[128];         // h2[0..49] dwords 0..49; dump region 64..127
    __shared__ __align__(16) float partial[64];

    const int tid = threadIdx.x;
    const int L  = tid & 63;
    const int m  = L & 15;          // MFMA row-in-tile / D col
    const int g  = L >> 4;          // MFMA k-group
    const int L2 = (L < 36) ? L : 35;

    // ---- stage embedded sequence as fp16 (both waves) ----
    for (int i = tid; i < SEQ * 5; i += TPB) {
        int t = i / 5, j = i - 5 * t;
        const float* ep = embed + x[t] * 10 + 2 * j;
        H2I c; c.h = half2_t{(_Float16)ep[0], (_Float16)ep[1]};
        seqbuf[t * 8 + j] = c.i;
    }
    // ---- init h buffer (fp16 pairs) + zero dump region ----
    if (tid < 128) {
        int v = 0;
        if (tid < 50) { H2I c; c.h = half2_t{(_Float16)hidden[2 * tid], (_Float16)hidden[2 * tid + 1]}; v = c.i; }
        hbuf[tid] = v;
    }

    // ---- persistent A fragments: rows = [Whr;Whz;Whn] (300x100), cols 0..95 ----
    half8_t afr[19][3];
    #pragma unroll
    for (int tt = 0; tt < 19; tt++) {
        int row = 16 * tt + m;
        #pragma unroll
        for (int kk = 0; kk < 3; kk++) {
            half8_t a;
            if (row < 300) {
                const float* s = w_hh + row * MID + 32 * kk + 8 * g;
                float4 f0 = *(const float4*)s;
                float4 f1 = *(const float4*)(s + 4);
                a = half8_t{(_Float16)f0.x, (_Float16)f0.y, (_Float16)f0.z, (_Float16)f0.w,
                            (_Float16)f1.x, (_Float16)f1.y, (_Float16)f1.z, (_Float16)f1.w};
            } else {
                a = half8_t{(_Float16)0.f, (_Float16)0.f, (_Float16)0.f, (_Float16)0.f,
                            (_Float16)0.f, (_Float16)0.f, (_Float16)0.f, (_Float16)0.f};
            }
            afr[tt][kk] = a;
        }
    }

    // ---- VALU tail weights: cols 96..99 of w_hh + all 10 of w_ih, for 6 rows ----
    half2_t wt[6][7];
    {
        const int rowsv[6] = { L, 100 + L, 200 + L, 64 + L2, 164 + L2, 264 + L2 };
        #pragma unroll
        for (int rr = 0; rr < 6; rr++) {
            const float* wh = w_hh + rowsv[rr] * MID + 96;
            wt[rr][0] = half2_t{(_Float16)wh[0], (_Float16)wh[1]};
            wt[rr][1] = half2_t{(_Float16)wh[2], (_Float16)wh[3]};
            const float* wi = w_ih + rowsv[rr] * 10;
            #pragma unroll
            for (int k = 0; k < 5; k++)
                wt[rr][2 + k] = half2_t{(_Float16)wi[2 * k], (_Float16)wi[2 * k + 1]};
        }
    }
    const float bias_r1 = b_ih[L]        + b_hh[L];
    const float bias_z1 = b_ih[100 + L]  + b_hh[100 + L];
    const float bias_in1 = b_ih[200 + L];
    const float bias_hn1 = b_hh[200 + L];
    const float bias_r2 = b_ih[64 + L2]  + b_hh[64 + L2];
    const float bias_z2 = b_ih[164 + L2] + b_hh[164 + L2];
    const float bias_in2 = b_ih[264 + L2];
    const float bias_hn2 = b_hh[264 + L2];

    float h1  = hidden[L];            // fp32 state, unit L
    float h2u = hidden[64 + L2];      // fp32 state, unit 64+L (valid L<36)
    const float fw1 = fc_w[L];
    const float fw2 = fc_w[64 + L2];

    char*       gB    = (char*)gates;
    char*       gw    = gB + 16 * g;          // D-store v_addr (col-0 lanes)
    const char* gr    = gB + 4 * L;           // gate-read v_addr
    const char* hB    = (const char*)hbuf;
    const char* bread = hB + 16 * g;          // B-fragment v_addr
    const int hw1 = ((L & 1) == 0) ? 2 * L : 256 + 4 * L;                  // byte addr (dump if odd)
    const int hw2 = (((L & 1) == 0) && (L < 36)) ? 128 + 2 * L : 256 + 4 * L;

    __syncthreads();

    if (tid < 64) {
        const f32x4 zf = {0.f, 0.f, 0.f, 0.f};
        #pragma unroll 1
        for (int t = 0; t < SEQ; t++) {
            // B fragments: h cols 0..95 (broadcast within 16-lane groups, conflict-free)
            H8I b0, b1, b2;
            b0.i4 = *(const int4*)(bread);
            b1.i4 = *(const int4*)(bread + 64);
            b2.i4 = *(const int4*)(bread + 128);
            // tail inputs: h cols 96..99 + e_t (broadcast reads)
            int2 ht = *(const int2*)(hB + 192);
            const int* eb = seqbuf + t * 8;
            int4 e4 = *(const int4*)eb;
            int  e1 = eb[4];
            half2_t tv[7] = { i2h(ht.x), i2h(ht.y),
                              i2h(e4.x), i2h(e4.y), i2h(e4.z), i2h(e4.w), i2h(e1) };

            // 57 MFMA on the matrix pipe; gates rows 0..303 land in LDS
            mfma_group<0, 5>(afr, b0.h8, b1.h8, b2.h8, zf, gw, m);
            mfma_group<5, 5>(afr, b0.h8, b1.h8, b2.h8, zf, gw, m);
            mfma_group<10, 5>(afr, b0.h8, b1.h8, b2.h8, zf, gw, m);
            mfma_group<15, 4>(afr, b0.h8, b1.h8, b2.h8, zf, gw, m);

            // VALU tail dots (independent of MFMA -> co-issue)
            float ar1 = bias_r1, az1 = bias_z1, ar2 = bias_r2, az2 = bias_z2;
            #pragma unroll
            for (int k = 0; k < 7; k++) {
                ar1 = fdot2(wt[0][k], tv[k], ar1);
                az1 = fdot2(wt[1][k], tv[k], az1);
                ar2 = fdot2(wt[3][k], tv[k], ar2);
                az2 = fdot2(wt[4][k], tv[k], az2);
            }
            float ghn1 = fdot2(wt[2][0], tv[0], bias_hn1); ghn1 = fdot2(wt[2][1], tv[1], ghn1);
            float ghn2 = fdot2(wt[5][0], tv[0], bias_hn2); ghn2 = fdot2(wt[5][1], tv[1], ghn2);
            float gin1 = bias_in1, gin2 = bias_in2;
            #pragma unroll
            for (int k = 2; k < 7; k++) {
                gin1 = fdot2(wt[2][k], tv[k], gin1);
                gin2 = fdot2(wt[5][k], tv[k], gin2);
            }

            // MFMA gate parts (same-wave LDS, in-order after the stores above)
            float mr1 = *(const float*)(gr);
            float mz1 = *(const float*)(gr + 400);
            float mn1 = *(const float*)(gr + 800);
            float mr2 = *(const float*)(gr + 256);
            float mz2 = *(const float*)(gr + 656);
            float mn2 = *(const float*)(gr + 1056);

            // mix (fp32 state)
            float r1 = sigm(mr1 + ar1);
            float z1 = sigm(mz1 + az1);
            float n1 = tanh_f(gin1 + r1 * (mn1 + ghn1));
            h1 = n1 + z1 * (h1 - n1);
            float r2 = sigm(mr2 + ar2);
            float z2 = sigm(mz2 + az2);
            float n2 = tanh_f(gin2 + r2 * (mn2 + ghn2));
            h2u = n2 + z2 * (h2u - n2);

            // republish h as fp16 pairs (DPP pack; odd lanes write to dump region)
            float h1n = pull_odd(h1);
            H2I p1; p1.h = half2_t{(_Float16)h1, (_Float16)h1n};
            *(int*)((char*)hbuf + hw1) = p1.i;
            float h2n = pull_odd(h2u);
            H2I p2; p2.h = half2_t{(_Float16)h2u, (_Float16)h2n};
            *(int*)((char*)hbuf + hw2) = p2.i;
        }

        // ---- epilogue: sigmoid(relu(h) . fc_w + fc_b) ----
        float acc = fmaxf(h1, 0.f) * fw1;
        if (L < 36) acc += fmaxf(h2u, 0.f) * fw2;
        partial[L] = acc;
        if (L == 0) {
            float s = fc_b[0];
            const float4* pp = (const float4*)partial;
            #pragma unroll
            for (int k = 0; k < 16; k++) {
                float4 f = pp[k];
                s += (f.x + f.y) + (f.z + f.w);
            }
            out[0] = sigm(s);
        }
    }
    __syncthreads();
}

extern "C" void kernel_launch(void* const* d_in, const int* in_sizes, int n_in,
                              void* d_out, int out_size, void* d_ws, size_t ws_size,
                              hipStream_t stream) {
    const int*   x      = (const int*)  d_in[0];
    const float* hidden = (const float*)d_in[1];
    const float* embed  = (const float*)d_in[2];
    const float* w_ih   = (const float*)d_in[3];
    const float* w_hh   = (const float*)d_in[4];
    const float* b_ih   = (const float*)d_in[5];
    const float* b_hh   = (const float*)d_in[6];
    const float* fc_w   = (const float*)d_in[7];
    const float* fc_b   = (const float*)d_in[8];
    float*       out    = (float*)d_out;

    gru_fused<<<1, TPB, 0, stream>>>(x, hidden, embed, w_ih, w_hh,
                                     b_ih, b_hh, fc_w, fc_b, out);
}

// Round 4
// 418.606 us; speedup vs baseline: 1.6391x; 1.6391x over previous
//
#include <hip/hip_runtime.h>

#define SEQ 550
#define MID 100
#define TPB 128

typedef _Float16 half2_t __attribute__((ext_vector_type(2)));
typedef _Float16 half8_t __attribute__((ext_vector_type(8)));
typedef float f32x4 __attribute__((ext_vector_type(4)));

union H2I { int i; half2_t h; };
union H8I { int4 i4; half8_t h8; };

__device__ __forceinline__ float fdot2(half2_t a, half2_t b, float c) {
    return __builtin_amdgcn_fdot2(a, b, c, false);
}
__device__ __forceinline__ float sigm(float x) { return 1.0f / (1.0f + __expf(-x)); }
__device__ __forceinline__ float tanh_f(float x) { return 1.0f - 2.0f / (__expf(2.0f * x) + 1.0f); }
__device__ __forceinline__ half2_t i2h(int v) { H2I u; u.i = v; return u.h; }

// Layout: wave w owns units [50w, 50w+50). 13 MFMA tiles (16x16x32 f16) per wave.
// Tile-row p = 4*qg + rt of tile t holds weight-row rt*100 + (50w + 13*qg + t)
// (rt=3 / overflow rows are zero). B cols 0..15 all replicated with h ->
// D identical across cols -> lane (g,m) holds, for every tile t, the {r,z,n}
// MFMA gate-parts of unit 50w+13g+t in its D quad regs 0..2. Lane (g,m)
// extracts tile t=m (compile-time cndmask chain), mixes unit 50w+13g+m,
// publishes one fp16 to the ping-pong h buffer. One barrier per step.

__global__ __launch_bounds__(TPB, 1) void gru_fused(
    const int*   __restrict__ x,
    const float* __restrict__ hidden,
    const float* __restrict__ embed,
    const float* __restrict__ w_ih,
    const float* __restrict__ w_hh,
    const float* __restrict__ b_ih,
    const float* __restrict__ b_hh,
    const float* __restrict__ fc_w,
    const float* __restrict__ fc_b,
    float*       __restrict__ out)
{
    __shared__ __align__(16) int  seqbuf[SEQ * 8];   // e_t: 5 packed half2 + pad, 32B stride
    __shared__ __align__(16) char hlds[512];         // 2 x 256B ping-pong: h[0..99] as fp16 at bytes 0..199
    __shared__ float partial[MID];

    const int tid = threadIdx.x;
    const int w   = tid >> 6;        // wave 0/1
    const int l   = tid & 63;
    const int m   = l & 15;          // A row-in-tile / D col
    const int g   = l >> 4;          // k-slice group / D row-block
    const int qg  = m >> 2;          // quad within tile (A-load view)
    const int rt  = m & 3;           // row type: 0=r,1=z,2=n,3=pad

    // ---- stage embedded sequence as fp16 ----
    for (int i = tid; i < SEQ * 5; i += TPB) {
        int t = i / 5, j = i - 5 * t;
        const float* ep = embed + x[t] * 10 + 2 * j;
        H2I c; c.h = half2_t{(_Float16)ep[0], (_Float16)ep[1]};
        seqbuf[t * 8 + j] = c.i;
    }

    // ---- A fragments: 13 tiles x 3 k-slices (h cols 0..95) ----
    half8_t afr[13][3];
    #pragma unroll
    for (int t = 0; t < 13; t++) {
        int j = 13 * qg + t;
        bool av = (rt < 3) && (j < 50);
        int wrow = rt * MID + 50 * w + (j < 50 ? j : 0);
        #pragma unroll
        for (int kk = 0; kk < 3; kk++) {
            half8_t a = half8_t{(_Float16)0.f, (_Float16)0.f, (_Float16)0.f, (_Float16)0.f,
                                (_Float16)0.f, (_Float16)0.f, (_Float16)0.f, (_Float16)0.f};
            if (av) {
                const float* s = w_hh + wrow * MID + 32 * kk + 8 * g;
                float4 f0 = *(const float4*)s;
                float4 f1 = *(const float4*)(s + 4);
                a = half8_t{(_Float16)f0.x, (_Float16)f0.y, (_Float16)f0.z, (_Float16)f0.w,
                            (_Float16)f1.x, (_Float16)f1.y, (_Float16)f1.z, (_Float16)f1.w};
            }
            afr[t][kk] = a;
        }
    }

    // ---- mixer identity + tail weights (h cols 96..99 + all 10 embed cols) ----
    const int  jm    = 13 * g + m;
    const bool ismix = (m < 13) && (jm < 50);
    const int  um    = 50 * w + (jm < 50 ? jm : 0);   // clamped global unit

    half2_t wtr[7], wtz[7], wtn[7];
    {
        const float* hr = w_hh + um * MID + 96;
        const float* hz = w_hh + (MID + um) * MID + 96;
        const float* hn = w_hh + (2 * MID + um) * MID + 96;
        wtr[0] = half2_t{(_Float16)hr[0], (_Float16)hr[1]};
        wtr[1] = half2_t{(_Float16)hr[2], (_Float16)hr[3]};
        wtz[0] = half2_t{(_Float16)hz[0], (_Float16)hz[1]};
        wtz[1] = half2_t{(_Float16)hz[2], (_Float16)hz[3]};
        wtn[0] = half2_t{(_Float16)hn[0], (_Float16)hn[1]};
        wtn[1] = half2_t{(_Float16)hn[2], (_Float16)hn[3]};
        const float* ir = w_ih + um * 10;
        const float* iz = w_ih + (MID + um) * 10;
        const float* in_ = w_ih + (2 * MID + um) * 10;
        #pragma unroll
        for (int k = 0; k < 5; k++) {
            wtr[2 + k] = half2_t{(_Float16)ir[2 * k], (_Float16)ir[2 * k + 1]};
            wtz[2 + k] = half2_t{(_Float16)iz[2 * k], (_Float16)iz[2 * k + 1]};
            wtn[2 + k] = half2_t{(_Float16)in_[2 * k], (_Float16)in_[2 * k + 1]};
        }
    }
    const float br  = b_ih[um]           + b_hh[um];
    const float bz  = b_ih[MID + um]     + b_hh[MID + um];
    const float bin = b_ih[2 * MID + um];
    const float bhn = b_hh[2 * MID + um];

    float hreg = hidden[um];
    const float fcw = fc_w[um];
    const float fcb = (tid == 0) ? fc_b[0] : 0.0f;

    // init h buffer 0
    if (ismix) *(_Float16*)(hlds + 2 * um) = (_Float16)hreg;

    __syncthreads();

    #pragma unroll 1
    for (int t = 0; t < SEQ; t++) {
        const char* rb = hlds + ((t & 1) << 8);
        // B fragments: h cols 0..95, broadcast within 16-lane groups
        H8I b0, b1, b2;
        b0.i4 = *(const int4*)(rb + 16 * g);
        b1.i4 = *(const int4*)(rb + 64 + 16 * g);
        b2.i4 = *(const int4*)(rb + 128 + 16 * g);
        // tail inputs: h cols 96..99 + e_t (same-address broadcasts)
        int2 ht = *(const int2*)(rb + 192);
        const int* eb = seqbuf + t * 8;
        int4 e4 = *(const int4*)eb;
        int  e1 = eb[4];
        half2_t tv0 = i2h(ht.x), tv1 = i2h(ht.y);
        half2_t tv2 = i2h(e4.x), tv3 = i2h(e4.y), tv4 = i2h(e4.z), tv5 = i2h(e4.w), tv6 = i2h(e1);

        // MFMA: 13 tiles x 3 chained k-slices; extract own quad via cndmask chain
        const f32x4 zf = {0.f, 0.f, 0.f, 0.f};
        float sr = 0.f, sz = 0.f, sn = 0.f;
        #pragma unroll
        for (int tt = 0; tt < 13; tt++) {
            f32x4 d = __builtin_amdgcn_mfma_f32_16x16x32_f16(afr[tt][0], b0.h8, zf, 0, 0, 0);
            d = __builtin_amdgcn_mfma_f32_16x16x32_f16(afr[tt][1], b1.h8, d, 0, 0, 0);
            d = __builtin_amdgcn_mfma_f32_16x16x32_f16(afr[tt][2], b2.h8, d, 0, 0, 0);
            bool c = (m == tt);
            sr = c ? d[0] : sr;
            sz = c ? d[1] : sz;
            sn = c ? d[2] : sn;
        }

        // VALU tail (co-issues under the MFMA pipe)
        float ar = br, az = bz, gin = bin, ghn = bhn;
        ar = fdot2(wtr[0], tv0, ar); ar = fdot2(wtr[1], tv1, ar);
        ar = fdot2(wtr[2], tv2, ar); ar = fdot2(wtr[3], tv3, ar);
        ar = fdot2(wtr[4], tv4, ar); ar = fdot2(wtr[5], tv5, ar);
        ar = fdot2(wtr[6], tv6, ar);
        az = fdot2(wtz[0], tv0, az); az = fdot2(wtz[1], tv1, az);
        az = fdot2(wtz[2], tv2, az); az = fdot2(wtz[3], tv3, az);
        az = fdot2(wtz[4], tv4, az); az = fdot2(wtz[5], tv5, az);
        az = fdot2(wtz[6], tv6, az);
        ghn = fdot2(wtn[0], tv0, ghn); ghn = fdot2(wtn[1], tv1, ghn);
        gin = fdot2(wtn[2], tv2, gin); gin = fdot2(wtn[3], tv3, gin);
        gin = fdot2(wtn[4], tv4, gin); gin = fdot2(wtn[5], tv5, gin);
        gin = fdot2(wtn[6], tv6, gin);

        // mix (fp32 state); computed by all lanes, written by mixers only
        float r = sigm(sr + ar);
        float z = sigm(sz + az);
        float n = tanh_f(gin + r * (sn + ghn));
        hreg = n + z * (hreg - n);
        if (ismix)
            *(_Float16*)(hlds + (((t & 1) ^ 1) << 8) + 2 * um) = (_Float16)hreg;

        __syncthreads();   // single 2-wave barrier per step
    }

    // ---- epilogue: sigmoid(relu(h) . fc_w + fc_b) ----
    if (ismix) partial[um] = fmaxf(hreg, 0.f) * fcw;
    __syncthreads();
    if (tid == 0) {
        float s = fcb;
        const float4* pp = (const float4*)partial;
        #pragma unroll
        for (int k = 0; k < 25; k++) {
            float4 f = pp[k];
            s += (f.x + f.y) + (f.z + f.w);
        }
        out[0] = sigm(s);
    }
}

extern "C" void kernel_launch(void* const* d_in, const int* in_sizes, int n_in,
                              void* d_out, int out_size, void* d_ws, size_t ws_size,
                              hipStream_t stream) {
    const int*   x      = (const int*)  d_in[0];
    const float* hidden = (const float*)d_in[1];
    const float* embed  = (const float*)d_in[2];
    const float* w_ih   = (const float*)d_in[3];
    const float* w_hh   = (const float*)d_in[4];
    const float* b_ih   = (const float*)d_in[5];
    const float* b_hh   = (const float*)d_in[6];
    const float* fc_w   = (const float*)d_in[7];
    const float* fc_b   = (const float*)d_in[8];
    float*       out    = (float*)d_out;

    gru_fused<<<1, TPB, 0, stream>>>(x, hidden, embed, w_ih, w_hh,
                                     b_ih, b_hh, fc_w, fc_b, out);
}